// Round 10
// baseline (124.399 us; speedup 1.0000x reference)
//
#include <hip/hip_runtime.h>
#include <math.h>

#define B_ 64
#define P_ 24564
#define G_ 48

// Workspace layout (total ~0.62 MB), everything overwritten/initialized every call (no memset):
//   [0]      unsigned long long bkey[B_][G_][NCH]   per-(b,g,chunk) best-prior keys
//   [589824] float        pl[NBLK]                  per-block loss partials
//   [595968] unsigned int pn[NBLK]                  per-block npos partials
//   [602112] double  acc_l ; [602120] uint acc_n ; [602124] uint done
//            (initialized by match block (0,0); fix runs after match -> visible)
constexpr int CH    = 1024;
constexpr int NCH   = 24;               // 24*1024 = 24576 >= P_
constexpr int PPT   = 4;
constexpr int NBLK  = NCH * B_;         // 1536
constexpr int ROW   = 132;              // kgrid row in u32 (128 entries + pad)

__device__ __forceinline__ float frcp(float x) { return __builtin_amdgcn_rcpf(x); }

// Smooth-ln repulsion term; identical in match (default) and fix (correction) so terms cancel.
__device__ __forceinline__ float loss_term(float4 pr, float4 l, float4 gb, float ga) {
    float cx = pr.x + l.x * 0.1f * pr.z;
    float cy = pr.y + l.y * 0.1f * pr.w;
    float w  = pr.z * expf(l.z * 0.2f);
    float h  = pr.w * expf(l.w * 0.2f);
    float dx1 = cx - w * 0.5f, dy1 = cy - h * 0.5f;
    float dx2 = cx + w * 0.5f, dy2 = cy + h * 0.5f;
    float ix1 = fmaxf(gb.x, dx1), iy1 = fmaxf(gb.y, dy1);
    float ix2 = fminf(gb.z, dx2), iy2 = fminf(gb.w, dy2);
    float iw = fmaxf(ix2 - ix1, 0.0f), ih = fmaxf(iy2 - iy1, 0.0f);
    float iogv = (iw * ih) * frcp(ga + 1e-7f);
    float r = 0.0f;
    if (iogv < 0.95f) {
        if (iogv < 0.5f)
            r = -logf(1.0f - iogv + 1e-7f);
        else
            r = (iogv - 0.5f) * 2.0f + 0.69314718055994531f;  // -ln(0.5)
    }
    return r;
}

// Packed top-2 over g of r = inter/(ga+pa): key=(bits(r)&~0x3F)|(63-g). Shared by both
// kernels so fix's recompute reproduces match's i1/i2/pos decisions (incl. tie-breaks).
__device__ __forceinline__ void top2_step(float4 gb, float ga, float px1, float py1,
                                          float px2, float py2, float pa, int g,
                                          unsigned int& k1, unsigned int& k2) {
    float ix1 = fmaxf(gb.x, px1), iy1 = fmaxf(gb.y, py1);
    float ix2 = fminf(gb.z, px2), iy2 = fminf(gb.w, py2);
    float iw = fmaxf(ix2 - ix1, 0.0f), ih = fmaxf(iy2 - iy1, 0.0f);
    float inter = iw * ih;
    float r = inter * frcp(ga + pa);
    unsigned int pk = (__float_as_uint(r) & 0xFFFFFFC0u) | (unsigned)(63 - g);
    k2 = max(k2, min(k1, pk));
    k1 = max(k1, pk);
}

// ---------------- K1: fused — top-2 per prior, per-gt block argmax, default loss ------------
__global__ __launch_bounds__(256) void match_kernel(
    const float* __restrict__ pred_loc, const float* __restrict__ priors,
    const float* __restrict__ gt, unsigned long long* __restrict__ bkey,
    float* __restrict__ pl, unsigned int* __restrict__ pn,
    double* __restrict__ acc_l, unsigned int* __restrict__ acc_n,
    unsigned int* __restrict__ done) {
    const int b    = blockIdx.y;
    const int base = blockIdx.x * CH;
    const int tid  = threadIdx.x;

    // init the cross-kernel accumulators (any single block; visible at kernel boundary)
    if (blockIdx.x == 0 && blockIdx.y == 0 && tid == 0) {
        *acc_l = 0.0; *acc_n = 0u; *done = 0u;
    }

    __shared__ float4 sbox[G_];
    __shared__ float  sga[G_];
    __shared__ unsigned int kgrid[G_ * ROW];   // pair-reduced per-gt candidate keys
    __shared__ unsigned int pmax[G_][4];
    __shared__ float rs[4];
    __shared__ unsigned int rn[4];

    if (tid < G_) {
        const float* q = gt + ((size_t)b * G_ + tid) * 5;
        float x1 = q[0], y1 = q[1], x2 = q[2], y2 = q[3];
        sbox[tid] = make_float4(x1, y1, x2, y2);
        sga[tid]  = (x2 - x1) * (y2 - y1);
    }
    __syncthreads();

    float px1[PPT], py1[PPT], px2[PPT], py2[PPT], pa[PPT];
    unsigned int tb[PPT];  // 1023 - local_p (per-gt tie-break: lower p wins)
#pragma unroll
    for (int j = 0; j < PPT; j++) {
        int lp = tid + 256 * j;
        int pc = min(base + lp, P_ - 1);  // clamped OOB dup loses tie-break to the real one
        float4 pr = ((const float4*)priors)[pc];
        float hx = pr.z * 0.5f, hy = pr.w * 0.5f;
        px1[j] = pr.x - hx; py1[j] = pr.y - hy;
        px2[j] = pr.x + hx; py2[j] = pr.y + hy;
        pa[j] = (px2[j] - px1[j]) * (py2[j] - py1[j]);
        tb[j] = (unsigned)(1023 - lp);
    }

    unsigned int k1[PPT], k2[PPT];
#pragma unroll
    for (int j = 0; j < PPT; j++) { k1[j] = 0u; k2[j] = 0u; }

#pragma unroll 8
    for (int g = 0; g < G_; g++) {
        float4 gb = sbox[g];
        float  ga = sga[g];
        unsigned int gmax = 0u;
#pragma unroll
        for (int j = 0; j < PPT; j++) {
            float ix1 = fmaxf(gb.x, px1[j]), iy1 = fmaxf(gb.y, py1[j]);
            float ix2 = fminf(gb.z, px2[j]), iy2 = fminf(gb.w, py2[j]);
            float iw = fmaxf(ix2 - ix1, 0.0f), ih = fmaxf(iy2 - iy1, 0.0f);
            float inter = iw * ih;
            // r = inter/(ga+pa) is a monotone transform of IoU=inter/(ga+pa-inter)
            float r = inter * frcp(ga + pa[j]);
            unsigned int vb = __float_as_uint(r);
            unsigned int pk = (vb & 0xFFFFFFC0u) | (unsigned)(63 - g);
            k2[j] = max(k2[j], min(k1[j], pk));
            k1[j] = max(k1[j], pk);
            unsigned int gk = (vb & 0xFFFFFC00u) | tb[j];
            gmax = max(gmax, gk);
        }
        // pair-reduce across adjacent lanes, even lanes store -> 128-entry rows
        unsigned int o = __shfl_down(gmax, 1, 64);
        if ((tid & 1) == 0) kgrid[g * ROW + (tid >> 1)] = max(gmax, o);
    }

    // per-prior epilogue: default contribution assumes NO override (bi=i1 -> rep=i2)
    float contrib = 0.0f;
    unsigned int np = 0;
#pragma unroll
    for (int j = 0; j < PPT; j++) {
        int p = base + tid + 256 * j;
        unsigned int i2 = 63u - (k2[j] & 63u);
        // r >= 1/3  <=>  IoU >= 0.5 ; truncated-key threshold (bits(1/3f) & ~0x3F)
        unsigned int pos = (k1[j] >= 0x3EAAAA80u) ? 1u : 0u;
        if (p < P_ && pos) {
            float4 pr = ((const float4*)priors)[p];               // L1-hot reload
            float4 l  = ((const float4*)pred_loc)[(size_t)b * P_ + p];
            contrib += loss_term(pr, l, sbox[i2], sga[i2]);
            np++;
        }
    }

    const int lane = tid & 63, wv = tid >> 6;
    for (int off = 32; off; off >>= 1) {
        contrib += __shfl_down(contrib, off, 64);
        np      += __shfl_down(np, off, 64);
    }
    if (lane == 0) { rs[wv] = contrib; rn[wv] = np; }
    __syncthreads();  // kgrid + rs/rn visible

    // per-gt argmax within block: 4 readers per gt scan 32 entries each
    if (tid < 192) {
        int g = tid >> 2, qq = tid & 3;
        const uint4* row = (const uint4*)&kgrid[g * ROW + qq * 32];
        unsigned int m = 0u;
#pragma unroll
        for (int i = 0; i < 8; i++) {
            uint4 v = row[i];
            m = max(max(m, v.x), max(v.y, max(v.z, v.w)));
        }
        pmax[g][qq] = m;
    }
    __syncthreads();

    if (tid < G_) {
        unsigned int w = max(max(pmax[tid][0], pmax[tid][1]),
                             max(pmax[tid][2], pmax[tid][3]));
        int p = base + 1023 - (int)(w & 0x3FFu);
        p = min(p, P_ - 1);  // defensive; unreachable via tie-break
        float4 pr = ((const float4*)priors)[p];
        float hx = pr.z * 0.5f, hy = pr.w * 0.5f;
        float qx1 = pr.x - hx, qy1 = pr.y - hy, qx2 = pr.x + hx, qy2 = pr.y + hy;
        float pae = (qx2 - qx1) * (qy2 - qy1);
        float4 gb = sbox[tid];
        float ix1 = fmaxf(gb.x, qx1), iy1 = fmaxf(gb.y, qy1);
        float ix2 = fminf(gb.z, qx2), iy2 = fminf(gb.w, qy2);
        float iw = fmaxf(ix2 - ix1, 0.0f), ih = fmaxf(iy2 - iy1, 0.0f);
        float inter = iw * ih;
        // exact (bit-stable across blocks) IoU-form key for cross-block comparison
        float v = inter * frcp(sga[tid] + pae - inter);
        // layout [b][g][chunk]: fix kernel reads each (b,g)'s 24 keys contiguously
        bkey[((size_t)b * G_ + tid) * NCH + blockIdx.x] =
            ((unsigned long long)__float_as_uint(v) << 32) |
            (unsigned long long)(0xFFFFFFFFu - (unsigned)p);
    }

    if (tid == 0) {
        pl[b * NCH + blockIdx.x] = rs[0] + rs[1] + rs[2] + rs[3];
        pn[b * NCH + blockIdx.x] = rn[0] + rn[1] + rn[2] + rn[3];
    }
}

// ---------------- K2: per-image corrections + global fold + final (64 blocks) ---------------
__global__ __launch_bounds__(64) void fix_final_kernel(
    const float* __restrict__ pred_loc, const float* __restrict__ priors,
    const float* __restrict__ gt, const unsigned long long* __restrict__ bkey,
    const float* __restrict__ pl, const unsigned int* __restrict__ pn,
    double* __restrict__ acc_l, unsigned int* __restrict__ acc_n,
    unsigned int* __restrict__ done, float* __restrict__ out) {
    const int b = blockIdx.x, g = threadIdx.x;
    __shared__ float4 sbox[G_];
    __shared__ float  sga[G_];
    __shared__ int sp[G_];

    int p = -1;
    if (g < G_) {
        const float* q = gt + ((size_t)b * G_ + g) * 5;
        float x1 = q[0], y1 = q[1], x2 = q[2], y2 = q[3];
        sbox[g] = make_float4(x1, y1, x2, y2);
        sga[g]  = (x2 - x1) * (y2 - y1);
        const unsigned long long* row = bkey + ((size_t)b * G_ + g) * NCH;
        unsigned long long m = 0ull;
#pragma unroll
        for (int c = 0; c < NCH; c++) m = max(m, row[c]);
        p = (int)(0xFFFFFFFFu - (unsigned)(m & 0xFFFFFFFFull));
        sp[g] = p;
    }
    __syncthreads();

    double delta = 0.0;
    unsigned int dn = 0;
    if (g < G_) {
        // last-write-wins: g is alive iff no larger g' shares the same best prior
        bool alive = true;
        for (int d = g + 1; d < G_; d++)
            if (sp[d] == p) alive = false;
        if (alive) {
            // recompute this prior's top-2 with the same packed-key scheme as match
            float4 pr = ((const float4*)priors)[p];
            float hx = pr.z * 0.5f, hy = pr.w * 0.5f;
            float px1 = pr.x - hx, py1 = pr.y - hy;
            float px2 = pr.x + hx, py2 = pr.y + hy;
            float pa = (px2 - px1) * (py2 - py1);
            unsigned int k1 = 0u, k2 = 0u;
#pragma unroll 8
            for (int gg = 0; gg < G_; gg++)
                top2_step(sbox[gg], sga[gg], px1, py1, px2, py2, pa, gg, k1, k2);
            int i1 = (int)(63u - (k1 & 63u)), i2 = (int)(63u - (k2 & 63u));
            bool pos0 = (k1 >= 0x3EAAAA80u);
            int ri = (g == i1) ? i2 : i1;   // override bi=g -> rep flips to i1 unless g==i1
            float4 l = ((const float4*)pred_loc)[(size_t)b * P_ + p];
            float cnew = loss_term(pr, l, sbox[ri], sga[ri]);
            float cold = 0.0f;
            if (pos0) cold = loss_term(pr, l, sbox[i2], sga[i2]);  // cancels default term
            else      dn = 1;                                      // prior newly positive
            delta = (double)cnew - (double)cold;
        }
    }

    // fold this image's pl/pn slice (24 entries) into the same reduction
    if (g < NCH) { delta += (double)pl[b * NCH + g]; dn += pn[b * NCH + g]; }

    for (int off = 32; off; off >>= 1) {
        delta += __shfl_down(delta, off, 64);
        dn    += __shfl_down(dn, off, 64);
    }
    if (g == 0) {
        atomicAdd(acc_l, delta);          // 64 low-contention device-scope atomics
        atomicAdd(acc_n, dn);
        __threadfence();                  // release: our adds visible before counter bump
        unsigned int t = atomicAdd(done, 1u);
        if (t == (unsigned)(B_ - 1)) {
            __threadfence();              // acquire: all 64 blocks' adds visible
            double s = __hip_atomic_load(acc_l, __ATOMIC_RELAXED, __HIP_MEMORY_SCOPE_AGENT);
            unsigned int n = __hip_atomic_load(acc_n, __ATOMIC_RELAXED, __HIP_MEMORY_SCOPE_AGENT);
            out[0] = (float)(s / (double)n);
        }
    }
}

extern "C" void kernel_launch(void* const* d_in, const int* in_sizes, int n_in,
                              void* d_out, int out_size, void* d_ws, size_t ws_size,
                              hipStream_t stream) {
    const float* pred_loc = (const float*)d_in[0];  // [B,P,4]
    const float* priors   = (const float*)d_in[1];  // [P,4]
    const float* gt       = (const float*)d_in[2];  // [B,G,5]
    float* out = (float*)d_out;

    char* ws = (char*)d_ws;
    unsigned long long* bkey = (unsigned long long*)ws;                   // 589824 B
    float*        pl    = (float*)(ws + 589824);                          // 6144 B
    unsigned int* pn    = (unsigned int*)(ws + 595968);                   // 6144 B
    double*       acc_l = (double*)(ws + 602112);                         // 8 B
    unsigned int* acc_n = (unsigned int*)(ws + 602120);                   // 4 B
    unsigned int* done  = (unsigned int*)(ws + 602124);                   // 4 B

    dim3 g1(NCH, B_);
    match_kernel<<<g1, 256, 0, stream>>>(pred_loc, priors, gt, bkey, pl, pn,
                                         acc_l, acc_n, done);

    fix_final_kernel<<<B_, 64, 0, stream>>>(pred_loc, priors, gt, bkey, pl, pn,
                                            acc_l, acc_n, done, out);
}

// Round 11
// 123.820 us; speedup vs baseline: 1.0047x; 1.0047x over previous
//
#include <hip/hip_runtime.h>
#include <math.h>

#define B_ 64
#define P_ 24564
#define G_ 48

// Workspace layout (total ~0.62 MB), everything overwritten/initialized every call (no memset):
//   [0]      unsigned long long bkey[B_][G_][NCH]   per-(b,g,chunk) best-prior keys
//   [589824] float        pl[NBLK]                  per-block loss partials
//   [595968] unsigned int pn[NBLK]                  per-block npos partials
//   [602112] double  acc_l ; [602120] uint acc_n ; [602124] uint done
//            (initialized by match block (0,0); fix runs after match -> visible)
constexpr int CH    = 1024;
constexpr int NCH   = 24;               // 24*1024 = 24576 >= P_
constexpr int PPT   = 4;
constexpr int NBLK  = NCH * B_;         // 1536
constexpr int ROW   = 132;              // kgrid row in u32 (128 entries + pad)

typedef float v2f __attribute__((ext_vector_type(2)));

__device__ __forceinline__ float frcp(float x) { return __builtin_amdgcn_rcpf(x); }

// Smooth-ln repulsion term; identical in match (default) and fix (correction) so terms cancel.
__device__ __forceinline__ float loss_term(float4 pr, float4 l, float4 gb, float ga) {
    float cx = pr.x + l.x * 0.1f * pr.z;
    float cy = pr.y + l.y * 0.1f * pr.w;
    float w  = pr.z * expf(l.z * 0.2f);
    float h  = pr.w * expf(l.w * 0.2f);
    float dx1 = cx - w * 0.5f, dy1 = cy - h * 0.5f;
    float dx2 = cx + w * 0.5f, dy2 = cy + h * 0.5f;
    float ix1 = fmaxf(gb.x, dx1), iy1 = fmaxf(gb.y, dy1);
    float ix2 = fminf(gb.z, dx2), iy2 = fminf(gb.w, dy2);
    float iw = fmaxf(ix2 - ix1, 0.0f), ih = fmaxf(iy2 - iy1, 0.0f);
    float iogv = (iw * ih) * frcp(ga + 1e-7f);
    float r = 0.0f;
    if (iogv < 0.95f) {
        if (iogv < 0.5f)
            r = -logf(1.0f - iogv + 1e-7f);
        else
            r = (iogv - 0.5f) * 2.0f + 0.69314718055994531f;  // -ln(0.5)
    }
    return r;
}

// Packed top-2 over g of r = inter/(ga+pa): key=(bits(r)&~0x3F)|(63-g). Shared by both
// kernels so fix's recompute reproduces match's i1/i2/pos decisions (incl. tie-breaks).
// (v_pk_* packed fp32 is bit-identical per lane to scalar, so scalar recompute matches.)
__device__ __forceinline__ void top2_step(float4 gb, float ga, float px1, float py1,
                                          float px2, float py2, float pa, int g,
                                          unsigned int& k1, unsigned int& k2) {
    float ix1 = fmaxf(gb.x, px1), iy1 = fmaxf(gb.y, py1);
    float ix2 = fminf(gb.z, px2), iy2 = fminf(gb.w, py2);
    float iw = fmaxf(ix2 - ix1, 0.0f), ih = fmaxf(iy2 - iy1, 0.0f);
    float inter = iw * ih;
    float r = inter * frcp(ga + pa);
    unsigned int pk = (__float_as_uint(r) & 0xFFFFFFC0u) | (unsigned)(63 - g);
    k2 = max(k2, min(k1, pk));
    k1 = max(k1, pk);
}

// ---------------- K1: fused — top-2 per prior, per-gt block argmax, default loss ------------
__global__ __launch_bounds__(256) void match_kernel(
    const float* __restrict__ pred_loc, const float* __restrict__ priors,
    const float* __restrict__ gt, unsigned long long* __restrict__ bkey,
    float* __restrict__ pl, unsigned int* __restrict__ pn,
    double* __restrict__ acc_l, unsigned int* __restrict__ acc_n,
    unsigned int* __restrict__ done) {
    const int b    = blockIdx.y;
    const int base = blockIdx.x * CH;
    const int tid  = threadIdx.x;

    // init the cross-kernel accumulators (any single block; visible at kernel boundary)
    if (blockIdx.x == 0 && blockIdx.y == 0 && tid == 0) {
        *acc_l = 0.0; *acc_n = 0u; *done = 0u;
    }

    __shared__ float4 sbox[G_];
    __shared__ float  sga[G_];
    __shared__ unsigned int kgrid[G_ * ROW];   // pair-reduced per-gt candidate keys
    __shared__ unsigned int pmax[G_][4];
    __shared__ float rs[4];
    __shared__ unsigned int rn[4];

    if (tid < G_) {
        const float* q = gt + ((size_t)b * G_ + tid) * 5;
        float x1 = q[0], y1 = q[1], x2 = q[2], y2 = q[3];
        sbox[tid] = make_float4(x1, y1, x2, y2);
        sga[tid]  = (x2 - x1) * (y2 - y1);
    }
    __syncthreads();

    // priors held as 2 packed pairs (float2) -> v_pk_* geometry in the hot loop
    v2f px1v[2], py1v[2], px2v[2], py2v[2], pav[2];
    unsigned int tb[PPT];  // 1023 - local_p (per-gt tie-break: lower p wins)
#pragma unroll
    for (int j = 0; j < PPT; j++) {
        int lp = tid + 256 * j;
        int pc = min(base + lp, P_ - 1);  // clamped OOB dup loses tie-break to the real one
        float4 pr = ((const float4*)priors)[pc];
        float hx = pr.z * 0.5f, hy = pr.w * 0.5f;
        int h = j >> 1, e = j & 1;
        px1v[h][e] = pr.x - hx; py1v[h][e] = pr.y - hy;
        px2v[h][e] = pr.x + hx; py2v[h][e] = pr.y + hy;
        pav[h][e]  = (pr.x + hx - (pr.x - hx)) * (pr.y + hy - (pr.y - hy));
        tb[j] = (unsigned)(1023 - lp);
    }

    unsigned int k1[PPT], k2[PPT];
#pragma unroll
    for (int j = 0; j < PPT; j++) { k1[j] = 0u; k2[j] = 0u; }

#pragma unroll 8
    for (int g = 0; g < G_; g++) {
        float4 gb = sbox[g];
        float  ga = sga[g];
        v2f gx1 = {gb.x, gb.x}, gy1 = {gb.y, gb.y};
        v2f gx2 = {gb.z, gb.z}, gy2 = {gb.w, gb.w};
        v2f gav = {ga, ga}, zero = {0.0f, 0.0f};
        unsigned int gmax = 0u;
#pragma unroll
        for (int h = 0; h < 2; h++) {
            v2f ix1 = __builtin_elementwise_max(px1v[h], gx1);
            v2f iy1 = __builtin_elementwise_max(py1v[h], gy1);
            v2f ix2 = __builtin_elementwise_min(px2v[h], gx2);
            v2f iy2 = __builtin_elementwise_min(py2v[h], gy2);
            v2f iw  = __builtin_elementwise_max(ix2 - ix1, zero);
            v2f ih  = __builtin_elementwise_max(iy2 - iy1, zero);
            v2f inter = iw * ih;
            v2f den   = pav[h] + gav;
#pragma unroll
            for (int e = 0; e < 2; e++) {
                int j = 2 * h + e;
                // r = inter/(ga+pa) is a monotone transform of IoU
                float r = inter[e] * frcp(den[e]);
                unsigned int vb = __float_as_uint(r);
                unsigned int pk = (vb & 0xFFFFFFC0u) | (unsigned)(63 - g);
                k2[j] = max(k2[j], min(k1[j], pk));
                k1[j] = max(k1[j], pk);
                gmax = max(gmax, (vb & 0xFFFFFC00u) | tb[j]);
            }
        }
        // pair-reduce across adjacent lanes, even lanes store -> 128-entry rows
        unsigned int o = __shfl_down(gmax, 1, 64);
        if ((tid & 1) == 0) kgrid[g * ROW + (tid >> 1)] = max(gmax, o);
    }

    // per-prior epilogue: default contribution assumes NO override (bi=i1 -> rep=i2)
    float contrib = 0.0f;
    unsigned int np = 0;
#pragma unroll
    for (int j = 0; j < PPT; j++) {
        int p = base + tid + 256 * j;
        unsigned int i2 = 63u - (k2[j] & 63u);
        // r >= 1/3  <=>  IoU >= 0.5 ; truncated-key threshold (bits(1/3f) & ~0x3F)
        unsigned int pos = (k1[j] >= 0x3EAAAA80u) ? 1u : 0u;
        if (p < P_ && pos) {
            float4 pr = ((const float4*)priors)[p];               // L1-hot reload
            float4 l  = ((const float4*)pred_loc)[(size_t)b * P_ + p];
            contrib += loss_term(pr, l, sbox[i2], sga[i2]);
            np++;
        }
    }

    const int lane = tid & 63, wv = tid >> 6;
    for (int off = 32; off; off >>= 1) {
        contrib += __shfl_down(contrib, off, 64);
        np      += __shfl_down(np, off, 64);
    }
    if (lane == 0) { rs[wv] = contrib; rn[wv] = np; }
    __syncthreads();  // kgrid + rs/rn visible

    // per-gt argmax within block: 4 readers per gt scan 32 entries each
    if (tid < 192) {
        int g = tid >> 2, qq = tid & 3;
        const uint4* row = (const uint4*)&kgrid[g * ROW + qq * 32];
        unsigned int m = 0u;
#pragma unroll
        for (int i = 0; i < 8; i++) {
            uint4 v = row[i];
            m = max(max(m, v.x), max(v.y, max(v.z, v.w)));
        }
        pmax[g][qq] = m;
    }
    __syncthreads();

    if (tid < G_) {
        unsigned int w = max(max(pmax[tid][0], pmax[tid][1]),
                             max(pmax[tid][2], pmax[tid][3]));
        int p = base + 1023 - (int)(w & 0x3FFu);
        p = min(p, P_ - 1);  // defensive; unreachable via tie-break
        float4 pr = ((const float4*)priors)[p];
        float hx = pr.z * 0.5f, hy = pr.w * 0.5f;
        float qx1 = pr.x - hx, qy1 = pr.y - hy, qx2 = pr.x + hx, qy2 = pr.y + hy;
        float pae = (qx2 - qx1) * (qy2 - qy1);
        float4 gb = sbox[tid];
        float ix1 = fmaxf(gb.x, qx1), iy1 = fmaxf(gb.y, qy1);
        float ix2 = fminf(gb.z, qx2), iy2 = fminf(gb.w, qy2);
        float iw = fmaxf(ix2 - ix1, 0.0f), ih = fmaxf(iy2 - iy1, 0.0f);
        float inter = iw * ih;
        // exact (bit-stable across blocks) IoU-form key for cross-block comparison
        float v = inter * frcp(sga[tid] + pae - inter);
        // layout [b][g][chunk]: fix kernel reads each (b,g)'s 24 keys contiguously
        bkey[((size_t)b * G_ + tid) * NCH + blockIdx.x] =
            ((unsigned long long)__float_as_uint(v) << 32) |
            (unsigned long long)(0xFFFFFFFFu - (unsigned)p);
    }

    if (tid == 0) {
        pl[b * NCH + blockIdx.x] = rs[0] + rs[1] + rs[2] + rs[3];
        pn[b * NCH + blockIdx.x] = rn[0] + rn[1] + rn[2] + rn[3];
    }
}

// ---------------- K2: per-image corrections + global fold + final (64 blocks) ---------------
__global__ __launch_bounds__(64) void fix_final_kernel(
    const float* __restrict__ pred_loc, const float* __restrict__ priors,
    const float* __restrict__ gt, const unsigned long long* __restrict__ bkey,
    const float* __restrict__ pl, const unsigned int* __restrict__ pn,
    double* __restrict__ acc_l, unsigned int* __restrict__ acc_n,
    unsigned int* __restrict__ done, float* __restrict__ out) {
    const int b = blockIdx.x, g = threadIdx.x;
    __shared__ float4 sbox[G_];
    __shared__ float  sga[G_];
    __shared__ int sp[G_];

    int p = -1;
    if (g < G_) {
        const float* q = gt + ((size_t)b * G_ + g) * 5;
        float x1 = q[0], y1 = q[1], x2 = q[2], y2 = q[3];
        sbox[g] = make_float4(x1, y1, x2, y2);
        sga[g]  = (x2 - x1) * (y2 - y1);
        const unsigned long long* row = bkey + ((size_t)b * G_ + g) * NCH;
        unsigned long long m = 0ull;
#pragma unroll
        for (int c = 0; c < NCH; c++) m = max(m, row[c]);
        p = (int)(0xFFFFFFFFu - (unsigned)(m & 0xFFFFFFFFull));
        sp[g] = p;
    }
    __syncthreads();

    double delta = 0.0;
    unsigned int dn = 0;
    if (g < G_) {
        // last-write-wins: g is alive iff no larger g' shares the same best prior
        bool alive = true;
        for (int d = g + 1; d < G_; d++)
            if (sp[d] == p) alive = false;
        if (alive) {
            // recompute this prior's top-2 with the same packed-key scheme as match
            float4 pr = ((const float4*)priors)[p];
            float hx = pr.z * 0.5f, hy = pr.w * 0.5f;
            float px1 = pr.x - hx, py1 = pr.y - hy;
            float px2 = pr.x + hx, py2 = pr.y + hy;
            float pa = (px2 - px1) * (py2 - py1);
            unsigned int k1 = 0u, k2 = 0u;
#pragma unroll 8
            for (int gg = 0; gg < G_; gg++)
                top2_step(sbox[gg], sga[gg], px1, py1, px2, py2, pa, gg, k1, k2);
            int i1 = (int)(63u - (k1 & 63u)), i2 = (int)(63u - (k2 & 63u));
            bool pos0 = (k1 >= 0x3EAAAA80u);
            int ri = (g == i1) ? i2 : i1;   // override bi=g -> rep flips to i1 unless g==i1
            float4 l = ((const float4*)pred_loc)[(size_t)b * P_ + p];
            float cnew = loss_term(pr, l, sbox[ri], sga[ri]);
            float cold = 0.0f;
            if (pos0) cold = loss_term(pr, l, sbox[i2], sga[i2]);  // cancels default term
            else      dn = 1;                                      // prior newly positive
            delta = (double)cnew - (double)cold;
        }
    }

    // fold this image's pl/pn slice (24 entries) into the same reduction
    if (g < NCH) { delta += (double)pl[b * NCH + g]; dn += pn[b * NCH + g]; }

    for (int off = 32; off; off >>= 1) {
        delta += __shfl_down(delta, off, 64);
        dn    += __shfl_down(dn, off, 64);
    }
    if (g == 0) {
        atomicAdd(acc_l, delta);          // 64 low-contention device-scope atomics
        atomicAdd(acc_n, dn);
        __threadfence();                  // release: our adds visible before counter bump
        unsigned int t = atomicAdd(done, 1u);
        if (t == (unsigned)(B_ - 1)) {
            __threadfence();              // acquire: all 64 blocks' adds visible
            double s = __hip_atomic_load(acc_l, __ATOMIC_RELAXED, __HIP_MEMORY_SCOPE_AGENT);
            unsigned int n = __hip_atomic_load(acc_n, __ATOMIC_RELAXED, __HIP_MEMORY_SCOPE_AGENT);
            out[0] = (float)(s / (double)n);
        }
    }
}

extern "C" void kernel_launch(void* const* d_in, const int* in_sizes, int n_in,
                              void* d_out, int out_size, void* d_ws, size_t ws_size,
                              hipStream_t stream) {
    const float* pred_loc = (const float*)d_in[0];  // [B,P,4]
    const float* priors   = (const float*)d_in[1];  // [P,4]
    const float* gt       = (const float*)d_in[2];  // [B,G,5]
    float* out = (float*)d_out;

    char* ws = (char*)d_ws;
    unsigned long long* bkey = (unsigned long long*)ws;                   // 589824 B
    float*        pl    = (float*)(ws + 589824);                          // 6144 B
    unsigned int* pn    = (unsigned int*)(ws + 595968);                   // 6144 B
    double*       acc_l = (double*)(ws + 602112);                         // 8 B
    unsigned int* acc_n = (unsigned int*)(ws + 602120);                   // 4 B
    unsigned int* done  = (unsigned int*)(ws + 602124);                   // 4 B

    dim3 g1(NCH, B_);
    match_kernel<<<g1, 256, 0, stream>>>(pred_loc, priors, gt, bkey, pl, pn,
                                         acc_l, acc_n, done);

    fix_final_kernel<<<B_, 64, 0, stream>>>(pred_loc, priors, gt, bkey, pl, pn,
                                            acc_l, acc_n, done, out);
}